// Round 1
// baseline (49.787 us; speedup 1.0000x reference)
//
#include <hip/hip_runtime.h>

typedef __bf16 bf16x8 __attribute__((ext_vector_type(8)));
typedef float f32x16 __attribute__((ext_vector_type(16)));
typedef float f32x4 __attribute__((ext_vector_type(4)));

#define S_TOTAL 8192
#define DIM 256
#define BK 64

// Each block: one (batch, k-chunk). Computes full 256x256 partial C = sum_s A[s][i]*B[s][j]
// over its K-chunk using bf16 MFMA, writes f32 partial (scaled) to dst[blockIdx*65536].
// 1024 threads = 16 waves in a 4x4 grid; each wave owns a 64x64 output tile (2x2 of 32x32 MFMA).
__global__ __launch_bounds__(1024) void opm_partial(
    const float* __restrict__ A, const float* __restrict__ Bm,
    float* __restrict__ dst, int split, int kc, float scale)
{
    // [kb=8][i=256][8 s-elems] bf16 subtiled layout: ds_write_b128 and ds_read_b128
    // are both lane-contiguous -> conflict-free.
    __shared__ __bf16 lds_a[8 * 256 * 8];
    __shared__ __bf16 lds_b[8 * 256 * 8];

    const int tid = threadIdx.x;
    const int w   = tid >> 6;
    const int l   = tid & 63;
    const int batch = blockIdx.x / split;
    const int sp    = blockIdx.x % split;
    const long long base = (long long)batch * S_TOTAL * DIM;
    const int s0 = sp * kc;

    const int wr = w >> 2, wc = w & 3;   // wave position in 4x4 grid
    const int g0 = w * 2;                // staging group pair

    f32x16 acc[2][2] = {};

    for (int it = 0; it < kc; it += BK) {
        // ---- stage BK=64 rows of A and B into LDS (f32 -> bf16) ----
        #pragma unroll
        for (int half = 0; half < 2; ++half) {
            const int g  = g0 + half;        // 0..31
            const int kb = g >> 2;           // 0..7  (8 s-rows each)
            const int i  = (g & 3) * 64 + l; // 0..255
            const int s  = s0 + it + kb * 8;
            const float* pa = A  + base + (long long)s * DIM + i;
            const float* pb = Bm + base + (long long)s * DIM + i;
            float fa[8], fb[8];
            #pragma unroll
            for (int e = 0; e < 8; ++e) { fa[e] = pa[e * DIM]; fb[e] = pb[e * DIM]; }
            bf16x8 va, vb;
            #pragma unroll
            for (int e = 0; e < 8; ++e) { va[e] = (__bf16)fa[e]; vb[e] = (__bf16)fb[e]; }
            *(bf16x8*)&lds_a[(kb * 256 + i) * 8] = va;
            *(bf16x8*)&lds_b[(kb * 256 + i) * 8] = vb;
        }
        __syncthreads();

        // ---- MFMA over 4 k-tiles of 16 ----
        const int lane31 = l & 31;
        #pragma unroll
        for (int t = 0; t < 4; ++t) {
            const int kb0 = t * 2 + (l >> 5);
            bf16x8 af[2], bfr[2];
            #pragma unroll
            for (int mi = 0; mi < 2; ++mi)
                af[mi] = *(const bf16x8*)&lds_a[(kb0 * 256 + wr * 64 + mi * 32 + lane31) * 8];
            #pragma unroll
            for (int nj = 0; nj < 2; ++nj)
                bfr[nj] = *(const bf16x8*)&lds_b[(kb0 * 256 + wc * 64 + nj * 32 + lane31) * 8];
            #pragma unroll
            for (int mi = 0; mi < 2; ++mi)
                #pragma unroll
                for (int nj = 0; nj < 2; ++nj)
                    acc[mi][nj] = __builtin_amdgcn_mfma_f32_32x32x16_bf16(
                        af[mi], bfr[nj], acc[mi][nj], 0, 0, 0);
        }
        __syncthreads();
    }

    // ---- epilogue: write partial tile ----
    float* o = dst + (long long)blockIdx.x * (256 * 256);
    #pragma unroll
    for (int mi = 0; mi < 2; ++mi)
    #pragma unroll
    for (int nj = 0; nj < 2; ++nj)
    #pragma unroll
    for (int r = 0; r < 16; ++r) {
        const int row = (r & 3) + 8 * (r >> 2) + 4 * (l >> 5);
        const int i = wr * 64 + mi * 32 + row;
        const int j = wc * 64 + nj * 32 + (l & 31);
        o[i * 256 + j] = acc[mi][nj][r] * scale;
    }
}

// Sum `split` partials per batch, scale by 1/8192. One float4 per thread.
__global__ __launch_bounds__(256) void opm_reduce(
    const float* __restrict__ ws, float* __restrict__ out, int split)
{
    const int idx = blockIdx.x * 256 + threadIdx.x;   // float4 index, 131072 total
    const int b = idx >> 14;                          // 16384 float4 per batch tile
    const int r = idx & 16383;
    const f32x4* p = (const f32x4*)ws + ((long long)b * split << 14) + r;
    f32x4 s = {0.f, 0.f, 0.f, 0.f};
    for (int sp = 0; sp < split; ++sp) s += p[(long long)sp << 14];
    s *= (1.0f / 8192.0f);
    ((f32x4*)out)[idx] = s;
}

extern "C" void kernel_launch(void* const* d_in, const int* in_sizes, int n_in,
                              void* d_out, int out_size, void* d_ws, size_t ws_size,
                              hipStream_t stream)
{
    (void)in_sizes; (void)n_in; (void)out_size;
    const float* A  = (const float*)d_in[0];
    const float* Bm = (const float*)d_in[1];
    float* out = (float*)d_out;

    const size_t per_split = 8ull * 256 * 256 * sizeof(float);  // 2 MB
    int split = 32;
    while (split > 1 && (size_t)split * per_split > ws_size) split >>= 1;

    if (split >= 2) {
        const int kc = S_TOTAL / split;
        opm_partial<<<8 * split, 1024, 0, stream>>>(A, Bm, (float*)d_ws, split, kc, 1.0f);
        opm_reduce<<<(8 * 256 * 256 / 4) / 256, 256, 0, stream>>>((const float*)d_ws, out, split);
    } else {
        // tiny-ws fallback: one block per batch over full K, write directly to out
        opm_partial<<<8, 1024, 0, stream>>>(A, Bm, out, 1, S_TOTAL, 1.0f / 8192.0f);
    }
}

// Round 2
// 41.757 us; speedup vs baseline: 1.1923x; 1.1923x over previous
//
#include <hip/hip_runtime.h>
#include <hip/hip_bf16.h>

typedef __bf16 bf16x8 __attribute__((ext_vector_type(8)));
typedef float f32x16 __attribute__((ext_vector_type(16)));
typedef float f32x4 __attribute__((ext_vector_type(4)));

#define S_TOTAL 8192
#define DIM 256
#define BK 32

// Each block: one (batch, k-chunk). Full 256x256 partial via bf16 MFMA.
// Staging: global_load_lds dwordx4 of raw f32 rows into double-buffered LDS
// [2][BK][256] f32 (linear; one DMA instr stages one full 1KB row).
// Counted vmcnt(4) + raw s_barrier keep next tile's loads in flight across
// the barrier (T3/T4 minimum 2-phase template). f32->bf16 conversion happens
// at fragment-read time (VALU is otherwise idle in this memory-bound kernel).
__global__ __launch_bounds__(1024) void opm_partial(
    const float* __restrict__ A, const float* __restrict__ Bm,
    __bf16* __restrict__ dstbf, float* __restrict__ dstf32,
    int split, int kc, float scale)
{
    __shared__ float ldsA[2][BK][DIM];   // 64 KB
    __shared__ float ldsB[2][BK][DIM];   // 64 KB

    const int tid = threadIdx.x;
    const int w   = tid >> 6;
    const int l   = tid & 63;
    const int batch = blockIdx.x / split;
    const int sp    = blockIdx.x % split;
    const long long base = (long long)batch * S_TOTAL * DIM;
    const int s0 = sp * kc;
    const int wr = w >> 2, wc = w & 3;     // wave position in 4x4 grid
    const int lane31 = l & 31;
    const int hi = l >> 5;
    const int niter = kc / BK;

    f32x16 acc[2][2] = {};

    // Issue 4 global_load_lds (dwordx4) per wave: 64 row-slots (32 A + 32 B),
    // wave w owns slots w*4..w*4+3 (waves 0-7 -> A rows, 8-15 -> B rows).
    auto stage = [&](int buf, int it) {
        #pragma unroll
        for (int q = 0; q < 4; ++q) {
            const int g = w * 4 + q;
            const int r = g & 31;
            const long long s = (long long)s0 + (long long)it * BK + r;
            const float* gp;
            const float* lp;
            if (g < 32) { gp = A  + base + s * DIM + l * 4; lp = &ldsA[buf][r][0]; }
            else        { gp = Bm + base + s * DIM + l * 4; lp = &ldsB[buf][r][0]; }
            __builtin_amdgcn_global_load_lds(
                (const __attribute__((address_space(1))) unsigned int*)gp,
                (__attribute__((address_space(3))) unsigned int*)lp, 16, 0, 0);
        }
    };

    auto compute = [&](int buf) {
        #pragma unroll
        for (int t = 0; t < 2; ++t) {          // two k-tiles of 16 within BK=32
            const int srow = t * 16 + hi * 8;
            bf16x8 af[2], bfv[2];
            #pragma unroll
            for (int mi = 0; mi < 2; ++mi) {
                const int i = wr * 64 + mi * 32 + lane31;
                #pragma unroll
                for (int e = 0; e < 8; ++e)
                    af[mi][e] = (__bf16)ldsA[buf][srow + e][i];
            }
            #pragma unroll
            for (int nj = 0; nj < 2; ++nj) {
                const int j = wc * 64 + nj * 32 + lane31;
                #pragma unroll
                for (int e = 0; e < 8; ++e)
                    bfv[nj][e] = (__bf16)ldsB[buf][srow + e][j];
            }
            #pragma unroll
            for (int mi = 0; mi < 2; ++mi)
                #pragma unroll
                for (int nj = 0; nj < 2; ++nj)
                    acc[mi][nj] = __builtin_amdgcn_mfma_f32_32x32x16_bf16(
                        af[mi], bfv[nj], acc[mi][nj], 0, 0, 0);
        }
    };

    stage(0, 0);
    for (int it = 0; it < niter; ++it) {
        const int cur = it & 1;
        if (it + 1 < niter) {
            stage(cur ^ 1, it + 1);
            asm volatile("s_waitcnt vmcnt(4)" ::: "memory");  // cur's 4 done, next's 4 in flight
        } else {
            asm volatile("s_waitcnt vmcnt(0)" ::: "memory");
        }
        __builtin_amdgcn_s_barrier();
        __builtin_amdgcn_sched_barrier(0);   // don't hoist ds_reads above the wait
        compute(cur);
        __builtin_amdgcn_sched_barrier(0);   // don't sink ds_reads below the barrier
        __builtin_amdgcn_s_barrier();
    }

    // ---- epilogue ----
    if (dstf32) {
        float* o = dstf32 + (long long)blockIdx.x * (256 * 256);
        #pragma unroll
        for (int mi = 0; mi < 2; ++mi)
        #pragma unroll
        for (int nj = 0; nj < 2; ++nj)
        #pragma unroll
        for (int r = 0; r < 16; ++r) {
            const int row = (r & 3) + 8 * (r >> 2) + 4 * hi;
            const int i = wr * 64 + mi * 32 + row;
            const int j = wc * 64 + nj * 32 + lane31;
            o[i * 256 + j] = acc[mi][nj][r] * scale;
        }
    } else {
        __bf16* o = dstbf + (long long)blockIdx.x * (256 * 256);
        #pragma unroll
        for (int mi = 0; mi < 2; ++mi)
        #pragma unroll
        for (int nj = 0; nj < 2; ++nj)
        #pragma unroll
        for (int r = 0; r < 16; ++r) {
            const int row = (r & 3) + 8 * (r >> 2) + 4 * hi;
            const int i = wr * 64 + mi * 32 + row;
            const int j = wc * 64 + nj * 32 + lane31;
            o[i * 256 + j] = (__bf16)(acc[mi][nj][r] * scale);
        }
    }
}

// Sum `split` bf16 partials per batch, scale by 1/8192. bf16x8 (16B) per lane.
__global__ __launch_bounds__(256) void opm_reduce(
    const __bf16* __restrict__ ws, float* __restrict__ out, int split)
{
    const int idx = blockIdx.x * 256 + threadIdx.x;   // 65536 groups of 8 f32
    const int b = idx >> 13;                          // 8192 groups per batch
    const int r = idx & 8191;
    const bf16x8* p = (const bf16x8*)ws + (long long)b * split * 8192 + r;
    float s[8] = {0.f, 0.f, 0.f, 0.f, 0.f, 0.f, 0.f, 0.f};
    for (int sp = 0; sp < split; ++sp) {
        bf16x8 v = p[(long long)sp * 8192];
        #pragma unroll
        for (int e = 0; e < 8; ++e) s[e] += (float)v[e];
    }
    f32x4 lo = { s[0], s[1], s[2], s[3] };
    f32x4 hiv = { s[4], s[5], s[6], s[7] };
    lo  *= (1.0f / 8192.0f);
    hiv *= (1.0f / 8192.0f);
    ((f32x4*)out)[idx * 2]     = lo;
    ((f32x4*)out)[idx * 2 + 1] = hiv;
}

extern "C" void kernel_launch(void* const* d_in, const int* in_sizes, int n_in,
                              void* d_out, int out_size, void* d_ws, size_t ws_size,
                              hipStream_t stream)
{
    (void)in_sizes; (void)n_in; (void)out_size;
    const float* A  = (const float*)d_in[0];
    const float* Bm = (const float*)d_in[1];
    float* out = (float*)d_out;

    int split = 32;
    while (split > 1 && (size_t)8 * split * 65536 * sizeof(__bf16) > ws_size) split >>= 1;

    if (split >= 2) {
        const int kc = S_TOTAL / split;
        opm_partial<<<8 * split, 1024, 0, stream>>>(A, Bm, (__bf16*)d_ws, nullptr, split, kc, 1.0f);
        opm_reduce<<<256, 256, 0, stream>>>((const __bf16*)d_ws, out, split);
    } else {
        // tiny-ws fallback: one block per batch over full K, f32 direct to out
        opm_partial<<<8, 1024, 0, stream>>>(A, Bm, nullptr, out, 1, S_TOTAL, 1.0f / 8192.0f);
    }
}